// Round 10
// baseline (394.565 us; speedup 1.0000x reference)
//
#include <hip/hip_runtime.h>

#define OBS_LEN 8
#define PRED_LEN 12
#define TILE_B 32
#define NTHREADS 256

typedef __attribute__((ext_vector_type(8))) short short8;  // 8 bf16
typedef __attribute__((ext_vector_type(4))) float floatx4;
typedef __attribute__((ext_vector_type(2))) float floatx2;
typedef __attribute__((ext_vector_type(2))) unsigned int u32x2;
typedef unsigned short u16;
typedef unsigned int u32;

#define L2E 1.442695040888963f

__device__ __forceinline__ u16 f2bf(float f) {
  __bf16 b = (__bf16)f;
  return __builtin_bit_cast(u16, b);
}
__device__ __forceinline__ float bf2f(u16 h) {
  return __builtin_bit_cast(float, ((u32)h) << 16);
}
__device__ __forceinline__ float rndbf(float f) { return (float)(__bf16)f; }

#if __has_builtin(__builtin_amdgcn_exp2f)
__device__ __forceinline__ float fexp2_(float x) { return __builtin_amdgcn_exp2f(x); }
#else
__device__ __forceinline__ float fexp2_(float x) { return exp2f(x); }
#endif
__device__ __forceinline__ floatx2 exp2v(floatx2 x) {
  floatx2 r;
  r.x = fexp2_(x.x);
  r.y = fexp2_(x.y);
  return r;
}
#if __has_builtin(__builtin_amdgcn_rcpf)
__device__ __forceinline__ floatx2 rcp2(floatx2 x) {  // raw v_rcp ~1ulp
  floatx2 r;
  r.x = __builtin_amdgcn_rcpf(x.x);
  r.y = __builtin_amdgcn_rcpf(x.y);
  return r;
}
#else
__device__ __forceinline__ floatx2 rcp2(floatx2 x) {
  return floatx2{1.0f / x.x, 1.0f / x.y};
}
#endif

__device__ __forceinline__ floatx4 mfma_bf(short8 a, short8 b, floatx4 c) {
  return __builtin_amdgcn_mfma_f32_16x16x32_bf16(a, b, c, 0, 0, 0);
}

// A-operand fragments (A[m=lane&15][k=quad*8+j]) for this wave's 4 gate tiles
// (gate = t*64 + u0 + l16), weights rounded to bf16 = the ref's operand rounding.
__device__ __forceinline__ void load_afrags(const float* __restrict__ W,
                                            short8 (&af)[4][2],
                                            int u0, int q, int l16) {
#pragma unroll
  for (int t = 0; t < 4; ++t)
#pragma unroll
    for (int kf = 0; kf < 2; ++kf) {
      const float* src = W + (t * 64 + u0 + l16) * 64 + kf * 32 + q * 8;
      const floatx4 w0 = *(const floatx4*)src;
      const floatx4 w1 = *(const floatx4*)(src + 4);
      short8 a;
#pragma unroll
      for (int j = 0; j < 4; ++j) {
        a[j] = (short)f2bf(w0[j]);
        a[j + 4] = (short)f2bf(w1[j]);
      }
      af[t][kf] = a;
    }
}

// Per-lane emb tables for the lane's B-frag k-slice (k = kf*32 + q*8 + j):
// packed bf16 (w0,w1) pairs + f32 bias. 16 u32 + 16 f32 regs, per phase.
__device__ __forceinline__ void load_xtab(const float* __restrict__ emb_w,
                                          const float* __restrict__ emb_b,
                                          u32 (&ewpk)[16], float (&ebv)[16], int q) {
#pragma unroll
  for (int kf = 0; kf < 2; ++kf)
#pragma unroll
    for (int j = 0; j < 8; ++j) {
      const int k = kf * 32 + q * 8 + j;
      ewpk[kf * 8 + j] =
          (u32)f2bf(emb_w[k * 2]) | ((u32)f2bf(emb_w[k * 2 + 1]) << 16);
      ebv[kf * 8 + j] = emb_b[k];
    }
}

// One LSTM step, ONE barrier. REL: rel via 2 aex-MFMAs on the same h B-frags
// (rows 0,1 of D = rel0,rel1 at q==0 lanes) -> shfl broadcast -> in-register
// bf16(x) B-frags (exact ref rounding chain). !REL: r from posS row.
template <bool REL>
__device__ __forceinline__ void lstm_step(
    const u16* __restrict__ rdh, u16* __restrict__ wrh,
    const float* __restrict__ posrow,
    const short8 (&afh)[4][2], const short8 (&afx)[4][2],
    const short8 (&aex)[2],
    const floatx4 (&bacc)[4],
    const u32 (&ewpk)[16], const float (&ebv)[16],
    floatx2 (&c)[2][2],
    float* __restrict__ outp, float b2p0, float b2p1,
    int q, int l16, int wv) {
#pragma unroll
  for (int n = 0; n < 2; ++n) {
    const int s = n * 16 + l16;
    const int sw = s & 7;
    const u16* hr = rdh + s * 64;
    const short8 hb0 = *(const short8*)(hr + ((q ^ sw) * 8));
    const short8 hb1 = *(const short8*)(hr + (((q + 4) ^ sw) * 8));
    float rb0, rb1;
    if (REL) {
      floatx4 z = {0.f, 0.f, 0.f, 0.f};
      z = mfma_bf(aex[0], hb0, z);
      z = mfma_bf(aex[1], hb1, z);
      const float r0 = __shfl(z[0], l16) + b2p0;  // lane l16 has q==0 rows
      const float r1 = __shfl(z[1], l16) + b2p1;
      if (q == 0 && wv == 0)
        *(floatx2*)(outp + s * 2) = floatx2{r0, r1};
      rb0 = rndbf(r0);
      rb1 = rndbf(r1);
    } else {
      const floatx2 rr = *(const floatx2*)(posrow + s * 2);
      rb0 = rndbf(rr.x);
      rb1 = rndbf(rr.y);
    }
    // h-MFMAs first: their latency hides the x-build VALU below
    floatx4 acc[4];
#pragma unroll
    for (int t = 0; t < 4; ++t) acc[t] = mfma_bf(afh[t][0], hb0, bacc[t]);
#pragma unroll
    for (int t = 0; t < 4; ++t) acc[t] = mfma_bf(afh[t][1], hb1, acc[t]);
    // x B-frag in-register: x[k] = bf16(rb0*w0[k] + (rb1*w1[k] + eb[k]))
    short8 xb0, xb1;
#pragma unroll
    for (int j = 0; j < 8; ++j) {
      const u32 p0 = ewpk[j];
      const float x0 = rb0 * bf2f((u16)(p0 & 0xffffu)) +
                       (rb1 * bf2f((u16)(p0 >> 16)) + ebv[j]);
      xb0[j] = (short)f2bf(x0);
      const u32 p1 = ewpk[8 + j];
      const float x1 = rb0 * bf2f((u16)(p1 & 0xffffu)) +
                       (rb1 * bf2f((u16)(p1 >> 16)) + ebv[8 + j]);
      xb1[j] = (short)f2bf(x1);
    }
#pragma unroll
    for (int t = 0; t < 4; ++t) acc[t] = mfma_bf(afx[t][0], xb0, acc[t]);
#pragma unroll
    for (int t = 0; t < 4; ++t) acc[t] = mfma_bf(afx[t][1], xb1, acc[t]);
    // pointwise: shared-denominator activations, packed pairs
    u32 hpk[2];
#pragma unroll
    for (int p = 0; p < 2; ++p) {
      const floatx2 iv = {acc[0][2 * p], acc[0][2 * p + 1]};
      const floatx2 fv = {acc[1][2 * p], acc[1][2 * p + 1]};
      const floatx2 gv = {acc[2][2 * p], acc[2][2 * p + 1]};
      const floatx2 ov = {acc[3][2 * p], acc[3][2 * p + 1]};
      const floatx2 ei = exp2v(iv * -L2E);
      const floatx2 ef = exp2v(fv * -L2E);
      const floatx2 eg = exp2v(gv * (2.0f * L2E));
      const floatx2 eo = exp2v(ov * -L2E);
      const floatx2 A = ei + 1.0f;   // 1/sig(i)
      const floatx2 F = ef + 1.0f;   // 1/sig(f)
      const floatx2 Bg = eg + 1.0f;  // tanh(g) = (eg-1)/Bg
      const floatx2 P = A * Bg;
      const floatx2 num = c[n][p] * P + (eg - 1.0f) * F;
      const floatx2 cn = num * rcp2(F * P);
      c[n][p] = cn;
      const floatx2 ec = exp2v(cn * (2.0f * L2E));
      const floatx2 h = (ec - 1.0f) * rcp2((eo + 1.0f) * (ec + 1.0f));
      hpk[p] = (u32)f2bf(h.x) | ((u32)f2bf(h.y) << 16);
    }
    *(u32x2*)(wrh + s * 64 + (((wv * 2 + (q >> 1)) ^ sw) * 8) + (q & 1) * 4) =
        u32x2{hpk[0], hpk[1]};
  }
  __syncthreads();  // single barrier: step k's reads done before k+1's writes
}

// (256,3): 168-reg budget. This structure measured 120 VGPR at (256,2) (R9,
// no spill, WRITE_SIZE == logical 6MB) -> fits 3 waves/SIMD with headroom.
// (256,4)=128 budget is the next experiment only if this stays spill-free.
__global__ void __launch_bounds__(NTHREADS, 3)
lstm_kernel(const float* __restrict__ obs_rel,
            const float* __restrict__ enc_emb_w, const float* __restrict__ enc_emb_b,
            const float* __restrict__ enc_w_ih, const float* __restrict__ enc_w_hh,
            const float* __restrict__ enc_b_ih, const float* __restrict__ enc_b_hh,
            const float* __restrict__ dec_emb_w, const float* __restrict__ dec_emb_b,
            const float* __restrict__ dec_w_ih, const float* __restrict__ dec_w_hh,
            const float* __restrict__ dec_b_ih, const float* __restrict__ dec_b_hh,
            const float* __restrict__ h2p_w, const float* __restrict__ h2p_b,
            float* __restrict__ out, int batch) {
  __shared__ __align__(16) u16 hS[2][TILE_B * 64];
  __shared__ __align__(16) float posS[OBS_LEN][TILE_B * 2];

  const int tid = threadIdx.x;
  const int wv = tid >> 6, lane = tid & 63;
  const int q = lane >> 4, l16 = lane & 15;
  const int u0 = wv << 4;
  const long S0 = (long)blockIdx.x * TILE_B;

  if (tid < 128) {  // stage all 8 encoder-step position rows (coalesced)
    const int t = tid >> 4, i = tid & 15;
    *(floatx4*)&posS[t][i * 4] =
        *(const floatx4*)(obs_rel + (long)t * batch * 2 + S0 * 2 + i * 4);
  }
  for (int i = tid; i < TILE_B * 64 / 2; i += NTHREADS) ((u32*)&hS[0][0])[i] = 0;

  short8 afh[4][2], afx[4][2], aex[2];
  floatx4 bacc[4];
  floatx2 c[2][2];
  u32 ewpk[16];
  float ebv[16];

  // ---- encoder constants
  load_afrags(enc_w_hh, afh, u0, q, l16);
  load_afrags(enc_w_ih, afx, u0, q, l16);
  load_xtab(enc_emb_w, enc_emb_b, ewpk, ebv, q);
#pragma unroll
  for (int t = 0; t < 4; ++t)
#pragma unroll
    for (int r = 0; r < 4; ++r) {
      const int g = t * 64 + u0 + q * 4 + r;
      bacc[t][r] = enc_b_ih[g] + enc_b_hh[g];
    }
  c[0][0] = c[0][1] = c[1][0] = c[1][1] = floatx2{0.f, 0.f};
  aex[0] = aex[1] = short8{0, 0, 0, 0, 0, 0, 0, 0};
  const float b2p0 = h2p_b[0], b2p1 = h2p_b[1];
  __syncthreads();  // posS + h0 visible

  int pb = 0;
#pragma unroll 1
  for (int t = 0; t < OBS_LEN; ++t) {
    lstm_step<false>(hS[pb], hS[pb ^ 1], posS[t], afh, afx, aex, bacc,
                     ewpk, ebv, c, nullptr, b2p0, b2p1, q, l16, wv);
    pb ^= 1;
  }

  // ---- decoder constants; aex = h2p rows as A-frag (m = l16 < 2)
  load_afrags(dec_w_hh, afh, u0, q, l16);
  load_afrags(dec_w_ih, afx, u0, q, l16);
  load_xtab(dec_emb_w, dec_emb_b, ewpk, ebv, q);
#pragma unroll
  for (int t = 0; t < 4; ++t)
#pragma unroll
    for (int r = 0; r < 4; ++r) {
      const int g = t * 64 + u0 + q * 4 + r;
      bacc[t][r] = dec_b_ih[g] + dec_b_hh[g];
    }
#pragma unroll
  for (int kf = 0; kf < 2; ++kf) {
    short8 a = {0, 0, 0, 0, 0, 0, 0, 0};
    if (l16 < 2) {
      const float* src = h2p_w + l16 * 64 + kf * 32 + q * 8;
#pragma unroll
      for (int j = 0; j < 8; ++j) a[j] = (short)f2bf(src[j]);
    }
    aex[kf] = a;
  }
  c[0][0] = c[0][1] = c[1][0] = c[1][1] = floatx2{0.f, 0.f};

  // decoder step 0: x = emb_dec(bf16(last_rel)), h = h_enc, c = 0
  lstm_step<false>(hS[pb], hS[pb ^ 1], posS[7], afh, afx, aex, bacc,
                   ewpk, ebv, c, nullptr, b2p0, b2p1, q, l16, wv);
  pb ^= 1;

  // decoder steps 1..11: rel_{j-1} (aex-MFMA) -> out + feedback, 1 barrier each
#pragma unroll 1
  for (int j = 1; j < PRED_LEN; ++j) {
    lstm_step<true>(hS[pb], hS[pb ^ 1], nullptr, afh, afx, aex, bacc,
                    ewpk, ebv, c,
                    out + (long)(j - 1) * batch * 2 + S0 * 2, b2p0, b2p1,
                    q, l16, wv);
    pb ^= 1;
  }

  // ---- trailing output: rel_pos[11] from h_12 (last step's barrier covers)
  {
    float* outp = out + (long)(PRED_LEN - 1) * batch * 2 + S0 * 2;
#pragma unroll
    for (int n = 0; n < 2; ++n) {
      const int s = n * 16 + l16;
      const int sw = s & 7;
      const u16* hr = &hS[pb][0] + s * 64;
      const short8 hb0 = *(const short8*)(hr + ((q ^ sw) * 8));
      const short8 hb1 = *(const short8*)(hr + (((q + 4) ^ sw) * 8));
      floatx4 z = {0.f, 0.f, 0.f, 0.f};
      z = mfma_bf(aex[0], hb0, z);
      z = mfma_bf(aex[1], hb1, z);
      if (q == 0 && wv == 0)
        *(floatx2*)(outp + s * 2) = floatx2{z[0] + b2p0, z[1] + b2p1};
    }
  }
}

extern "C" void kernel_launch(void* const* d_in, const int* in_sizes, int n_in,
                              void* d_out, int out_size, void* d_ws, size_t ws_size,
                              hipStream_t stream) {
  const float* obs_rel = (const float*)d_in[1];
  const int batch = in_sizes[1] / (OBS_LEN * 2);  // 65536

  const int blocks = batch / TILE_B;  // 2048
  hipLaunchKernelGGL(lstm_kernel, dim3(blocks), dim3(NTHREADS), 0, stream,
                     obs_rel,
                     (const float*)d_in[2], (const float*)d_in[3],
                     (const float*)d_in[4], (const float*)d_in[5],
                     (const float*)d_in[6], (const float*)d_in[7],
                     (const float*)d_in[8], (const float*)d_in[9],
                     (const float*)d_in[10], (const float*)d_in[11],
                     (const float*)d_in[12], (const float*)d_in[13],
                     (const float*)d_in[14], (const float*)d_in[15],
                     (float*)d_out, batch);
}

// Round 11
// 226.338 us; speedup vs baseline: 1.7433x; 1.7433x over previous
//
#include <hip/hip_runtime.h>

#define OBS_LEN 8
#define PRED_LEN 12
#define TILE_B 32
#define NTHREADS 256

typedef __attribute__((ext_vector_type(8))) short short8;  // 8 bf16
typedef __attribute__((ext_vector_type(4))) float floatx4;
typedef __attribute__((ext_vector_type(2))) float floatx2;
typedef __attribute__((ext_vector_type(4))) unsigned short ushortx4;
typedef __attribute__((ext_vector_type(2))) unsigned int u32x2;
typedef unsigned short u16;
typedef unsigned int u32;

#define L2E 1.442695040888963f

__device__ __forceinline__ u16 f2bf(float f) {
  __bf16 b = (__bf16)f;
  return __builtin_bit_cast(u16, b);
}
__device__ __forceinline__ float bf2f(u16 h) {
  return __builtin_bit_cast(float, ((u32)h) << 16);
}
__device__ __forceinline__ float rndbf(float f) { return (float)(__bf16)f; }

#if __has_builtin(__builtin_amdgcn_exp2f)
__device__ __forceinline__ float fexp2_(float x) { return __builtin_amdgcn_exp2f(x); }
#else
__device__ __forceinline__ float fexp2_(float x) { return exp2f(x); }
#endif
__device__ __forceinline__ floatx2 exp2v(floatx2 x) {
  floatx2 r;
  r.x = fexp2_(x.x);
  r.y = fexp2_(x.y);
  return r;
}
#if __has_builtin(__builtin_amdgcn_rcpf)
__device__ __forceinline__ floatx2 rcp2(floatx2 x) {  // raw v_rcp ~1ulp
  floatx2 r;
  r.x = __builtin_amdgcn_rcpf(x.x);
  r.y = __builtin_amdgcn_rcpf(x.y);
  return r;
}
#else
__device__ __forceinline__ floatx2 rcp2(floatx2 x) {
  return floatx2{1.0f / x.x, 1.0f / x.y};
}
#endif

__device__ __forceinline__ floatx4 mfma_bf(short8 a, short8 b, floatx4 c) {
  return __builtin_amdgcn_mfma_f32_16x16x32_bf16(a, b, c, 0, 0, 0);
}

// XOR-swizzled LDS row layout: sample row = 64 u16 (128B, bank-aligned);
// element u lives in 16B block (u>>3) ^ (s&7).
__device__ __forceinline__ int swz(int s, int b) {
  return s * 64 + ((b ^ (s & 7)) * 8);
}

// A-operand fragments (A[m=lane&15][k=quad*8+j]) for this wave's 4 gate tiles
// (gate = t*64 + u0 + l16), weights rounded to bf16 = the ref's operand rounding.
// These are MFMA-only operands -> live in the accum half of the register file.
__device__ __forceinline__ void load_afrags(const float* __restrict__ W,
                                            short8 (&af)[4][2],
                                            int u0, int q, int l16) {
#pragma unroll
  for (int t = 0; t < 4; ++t)
#pragma unroll
    for (int kf = 0; kf < 2; ++kf) {
      const float* src = W + (t * 64 + u0 + l16) * 64 + kf * 32 + q * 8;
      const floatx4 w0 = *(const floatx4*)src;
      const floatx4 w1 = *(const floatx4*)(src + 4);
      short8 a;
#pragma unroll
      for (int j = 0; j < 4; ++j) {
        a[j] = (short)f2bf(w0[j]);
        a[j + 4] = (short)f2bf(w1[j]);
      }
      af[t][kf] = a;
    }
}

// One cell step for this wave's 16-gate slice x 32 samples (n in {0,1}).
// Bias rides in the first MFMA's C operand, read per-t from LDS (wave-broadcast
// ds_read_b128, 4 distinct addrs/wave) -- NOT a persistent VGPR array: the
// 84-arch-VGPR split at (256,3) can't afford VALU-touched persistents.
__device__ __forceinline__ void cell_step(const u16* __restrict__ rdh,
                                          const u16* __restrict__ rdx,
                                          u16* __restrict__ wrh,
                                          const short8 (&afh)[4][2],
                                          const short8 (&afx)[4][2],
                                          const float* __restrict__ biasrow,
                                          floatx2 (&c)[2][2],
                                          int q, int l16, int wv, int u0) {
#pragma unroll
  for (int n = 0; n < 2; ++n) {
    const int s = n * 16 + l16;
    const int sw = s & 7;
    const u16* hr = rdh + s * 64;
    const u16* xr = rdx + s * 64;
    const short8 hb0 = *(const short8*)(hr + ((q ^ sw) * 8));
    const short8 hb1 = *(const short8*)(hr + (((q + 4) ^ sw) * 8));
    const short8 xb0 = *(const short8*)(xr + ((q ^ sw) * 8));
    const short8 xb1 = *(const short8*)(xr + (((q + 4) ^ sw) * 8));
    floatx4 acc[4];
#pragma unroll
    for (int t = 0; t < 4; ++t) {
      const floatx4 bias = *(const floatx4*)(biasrow + t * 64 + u0 + q * 4);
      acc[t] = mfma_bf(afh[t][0], hb0, bias);
    }
#pragma unroll
    for (int t = 0; t < 4; ++t) acc[t] = mfma_bf(afx[t][0], xb0, acc[t]);
#pragma unroll
    for (int t = 0; t < 4; ++t) acc[t] = mfma_bf(afh[t][1], hb1, acc[t]);
#pragma unroll
    for (int t = 0; t < 4; ++t) acc[t] = mfma_bf(afx[t][1], xb1, acc[t]);
    u32 hpk[2];
#pragma unroll
    for (int p = 0; p < 2; ++p) {
      const floatx2 iv = {acc[0][2 * p], acc[0][2 * p + 1]};
      const floatx2 fv = {acc[1][2 * p], acc[1][2 * p + 1]};
      const floatx2 gv = {acc[2][2 * p], acc[2][2 * p + 1]};
      const floatx2 ov = {acc[3][2 * p], acc[3][2 * p + 1]};
      const floatx2 ei = exp2v(iv * -L2E);
      const floatx2 ef = exp2v(fv * -L2E);
      const floatx2 eg = exp2v(gv * (2.0f * L2E));
      const floatx2 eo = exp2v(ov * -L2E);
      const floatx2 A = ei + 1.0f;   // 1/sig(i)
      const floatx2 F = ef + 1.0f;   // 1/sig(f)
      const floatx2 Bg = eg + 1.0f;  // tanh(g) = (eg-1)/Bg
      const floatx2 P = A * Bg;
      const floatx2 num = c[n][p] * P + (eg - 1.0f) * F;
      const floatx2 cn = num * rcp2(F * P);
      c[n][p] = cn;
      const floatx2 ec = exp2v(cn * (2.0f * L2E));
      const floatx2 h = (ec - 1.0f) * rcp2((eo + 1.0f) * (ec + 1.0f));
      hpk[p] = (u32)f2bf(h.x) | ((u32)f2bf(h.y) << 16);
    }
    // units u0+q*4..+3: block = wv*2 + (q>>1), lo/hi half by q&1
    *(u32x2*)(wrh + s * 64 + (((wv * 2 + (q >> 1)) ^ sw) * 8) + (q & 1) * 4) =
        u32x2{hpk[0], hpk[1]};
  }
}

// x[s][e] = bf16( rb@bf16(emb_w)^T + emb_b ); thread (s8,p8) does its swizzled
// 16B block (e = p8*8..p8*8+7) in one short8 store.
__device__ __forceinline__ void xgen8(float rb0, float rb1,
                                      const float* __restrict__ ew0,
                                      const float* __restrict__ ew1,
                                      const float* __restrict__ eb,
                                      u16* __restrict__ xw, int s8, int p8) {
  short8 v;
#pragma unroll
  for (int j = 0; j < 8; ++j) {
    const int e = p8 * 8 + j;
    v[j] = (short)f2bf(rb0 * ew0[e] + (rb1 * ew1[e] + eb[e]));
  }
  *(short8*)(xw + swz(s8, p8)) = v;
}

// rel = bf16(h)@bf16(h2p_w)^T + h2p_b, f32; 8 threads/sample, butterfly reduce
__device__ __forceinline__ void areldot(const u16* __restrict__ h,
                                        const floatx2* __restrict__ hwp,
                                        float b2p0, float b2p1, int s8, int p8,
                                        float& r0, float& r1) {
  const short8 hv = *(const short8*)(h + swz(s8, p8));
  floatx2 d = {0.f, 0.f};
#pragma unroll
  for (int j = 0; j < 8; ++j) d = hwp[p8 * 8 + j] * bf2f((u16)hv[j]) + d;
  d.x += __shfl_xor(d.x, 1);
  d.x += __shfl_xor(d.x, 2);
  d.x += __shfl_xor(d.x, 4);
  d.y += __shfl_xor(d.y, 1);
  d.y += __shfl_xor(d.y, 2);
  d.y += __shfl_xor(d.y, 4);
  r0 = d.x + b2p0;
  r1 = d.y + b2p1;
}

// (256,3): compiler splits 168 = 84 arch + 84 accum. MFMA-only data (A-frags,
// acc) lives in the accum half; everything VALU-touched must fit 84 arch regs.
// R8 measured 32MB spill-writes with bacc[4] persistent -> moved to LDS here.
__global__ void __launch_bounds__(NTHREADS, 3)
lstm_kernel(const float* __restrict__ obs_rel,
            const float* __restrict__ enc_emb_w, const float* __restrict__ enc_emb_b,
            const float* __restrict__ enc_w_ih, const float* __restrict__ enc_w_hh,
            const float* __restrict__ enc_b_ih, const float* __restrict__ enc_b_hh,
            const float* __restrict__ dec_emb_w, const float* __restrict__ dec_emb_b,
            const float* __restrict__ dec_w_ih, const float* __restrict__ dec_w_hh,
            const float* __restrict__ dec_b_ih, const float* __restrict__ dec_b_hh,
            const float* __restrict__ h2p_w, const float* __restrict__ h2p_b,
            float* __restrict__ out, int batch) {
  __shared__ __align__(16) u16 hS[2][TILE_B * 64];
  __shared__ __align__(16) u16 xS[2][TILE_B * 64];
  __shared__ __align__(16) float posS[OBS_LEN][TILE_B * 2];
  __shared__ __align__(16) float biasS[2][256];  // enc, dec gate bias (f32)
  __shared__ float ew0e[64], ew1e[64], ebe[64];
  __shared__ float ew0d[64], ew1d[64], ebd[64];
  __shared__ __align__(8) floatx2 hwp[64];

  const int tid = threadIdx.x;
  const int wv = tid >> 6, lane = tid & 63;
  const int q = lane >> 4, l16 = lane & 15;
  const int u0 = wv << 4;
  const int s8 = tid >> 3, p8 = tid & 7;
  const long S0 = (long)blockIdx.x * TILE_B;

  if (tid < 128) {  // stage all 8 encoder-step position rows (coalesced)
    const int t = tid >> 4, i = tid & 15;
    *(floatx4*)&posS[t][i * 4] =
        *(const floatx4*)(obs_rel + (long)t * batch * 2 + S0 * 2 + i * 4);
  }
  if (tid < 64) {  // emb/h2p tables: weights bf16-rounded (operands), biases f32
    ew0e[tid] = rndbf(enc_emb_w[tid * 2]);
    ew1e[tid] = rndbf(enc_emb_w[tid * 2 + 1]);
    ebe[tid] = enc_emb_b[tid];
    ew0d[tid] = rndbf(dec_emb_w[tid * 2]);
    ew1d[tid] = rndbf(dec_emb_w[tid * 2 + 1]);
    ebd[tid] = dec_emb_b[tid];
    hwp[tid] = floatx2{rndbf(h2p_w[tid]), rndbf(h2p_w[64 + tid])};
  }
  biasS[0][tid] = enc_b_ih[tid] + enc_b_hh[tid];
  biasS[1][tid] = dec_b_ih[tid] + dec_b_hh[tid];
  for (int i = tid; i < TILE_B * 64 / 2; i += NTHREADS) ((u32*)&hS[0][0])[i] = 0;

  short8 afh[4][2], afx[4][2];
  floatx2 c[2][2];
  load_afrags(enc_w_hh, afh, u0, q, l16);
  load_afrags(enc_w_ih, afx, u0, q, l16);
  c[0][0] = c[0][1] = c[1][0] = c[1][1] = floatx2{0.f, 0.f};
  const float b2p0 = h2p_b[0], b2p1 = h2p_b[1];
  __syncthreads();  // posS + tables + bias + h0 visible
  {
    const floatx2 rr = *(const floatx2*)(&posS[0][s8 * 2]);
    xgen8(rndbf(rr.x), rndbf(rr.y), ew0e, ew1e, ebe, xS[0], s8, p8);
  }
  __syncthreads();  // x(0) visible

  int pb = 0;
#pragma unroll 1
  for (int t = 0; t < OBS_LEN; ++t) {
    // produce x(t+1) into the other buffer (h-independent, overlaps MFMA);
    // t==7 produces the decoder step-0 input with dec tables into xS[0]
    const int tn = t + 1;
    const floatx2 rr = *(const floatx2*)(&posS[(tn < 8) ? tn : 7][s8 * 2]);
    if (tn < 8)
      xgen8(rndbf(rr.x), rndbf(rr.y), ew0e, ew1e, ebe, xS[tn & 1], s8, p8);
    else
      xgen8(rndbf(rr.x), rndbf(rr.y), ew0d, ew1d, ebd, xS[0], s8, p8);
    cell_step(hS[pb], xS[t & 1], hS[pb ^ 1], afh, afx, &biasS[0][0], c,
              q, l16, wv, u0);
    __syncthreads();
    pb ^= 1;
  }

  // ---- decoder weights; step 0 (x already staged in xS[0]), c reset to 0
  load_afrags(dec_w_hh, afh, u0, q, l16);
  load_afrags(dec_w_ih, afx, u0, q, l16);
  c[0][0] = c[0][1] = c[1][0] = c[1][1] = floatx2{0.f, 0.f};
  cell_step(hS[pb], xS[0], hS[pb ^ 1], afh, afx, &biasS[1][0], c,
            q, l16, wv, u0);
  __syncthreads();
  pb ^= 1;

  // ---- decoder steps 1..11: rel (f32 out) + x_j regen, then cell step
#pragma unroll 1
  for (int j = 1; j < PRED_LEN; ++j) {
    float r0, r1;
    areldot(hS[pb], hwp, b2p0, b2p1, s8, p8, r0, r1);
    if (p8 == 0)
      *(floatx2*)(out + (long)(j - 1) * batch * 2 + (S0 + s8) * 2) = floatx2{r0, r1};
    xgen8(rndbf(r0), rndbf(r1), ew0d, ew1d, ebd, xS[0], s8, p8);
    __syncthreads();  // xS[0] ready
    cell_step(hS[pb], xS[0], hS[pb ^ 1], afh, afx, &biasS[1][0], c,
              q, l16, wv, u0);
    __syncthreads();  // h_{j+1} ready
    pb ^= 1;
  }

  // ---- trailing output: rel_pos[11] from h_12
  {
    float r0, r1;
    areldot(hS[pb], hwp, b2p0, b2p1, s8, p8, r0, r1);
    if (p8 == 0)
      *(floatx2*)(out + (long)(PRED_LEN - 1) * batch * 2 + (S0 + s8) * 2) =
          floatx2{r0, r1};
  }
}

extern "C" void kernel_launch(void* const* d_in, const int* in_sizes, int n_in,
                              void* d_out, int out_size, void* d_ws, size_t ws_size,
                              hipStream_t stream) {
  const float* obs_rel = (const float*)d_in[1];
  const int batch = in_sizes[1] / (OBS_LEN * 2);  // 65536

  const int blocks = batch / TILE_B;  // 2048
  hipLaunchKernelGGL(lstm_kernel, dim3(blocks), dim3(NTHREADS), 0, stream,
                     obs_rel,
                     (const float*)d_in[2], (const float*)d_in[3],
                     (const float*)d_in[4], (const float*)d_in[5],
                     (const float*)d_in[6], (const float*)d_in[7],
                     (const float*)d_in[8], (const float*)d_in[9],
                     (const float*)d_in[10], (const float*)d_in[11],
                     (const float*)d_in[12], (const float*)d_in[13],
                     (const float*)d_in[14], (const float*)d_in[15],
                     (float*)d_out, batch);
}